// Round 3
// baseline (150.221 us; speedup 1.0000x reference)
//
#include <hip/hip_runtime.h>

// Problem constants
#define HGT 256
#define WID 256
#define CH  64
#define NB  2
#define HW  (HGT * WID)
#define NODES (NB * HW)
#define NEG_SLOPE 0.2f

// packed intermediate: hfeat as bf16, layout [b][q=c/4][h*w][4ch] -> one uint2 (8B) per (q,pixel)

__device__ __forceinline__ unsigned short f2bf(float f) {
    union { float f; unsigned u; } v; v.f = f;
    unsigned r = v.u + 0x7FFF + ((v.u >> 16) & 1);   // RNE
    return (unsigned short)(r >> 16);
}

// ---------------------------------------------------------------------------
// Kernel A: hfeat = (x + pe) @ lin_w  (packed bf16 quads), a_src/a_dst dots.
// Block 256 = 64 px (tx) x 4 co-groups of 16 (ty). Grid 2048 (8 blocks/CU).
// x tile staged in LDS once per block (16 loads/thread, no redundant reads).
// Weights via wave-uniform scalar loads. pe@lin_w is rank-2: py*W0+px*W1+Bc.
// ---------------------------------------------------------------------------
__global__ __launch_bounds__(256) void gat_feat(
    const float* __restrict__ x, const float* __restrict__ pos_w,
    const float* __restrict__ pos_b, const float* __restrict__ lin_w,
    const float* __restrict__ att_src, const float* __restrict__ att_dst,
    unsigned short* __restrict__ hfeat, float* __restrict__ asrc,
    float* __restrict__ adst)
{
    __shared__ float xs[CH][64];               // 16 KB
    __shared__ float W0[CH], W1[CH], Bc[CH];
    __shared__ float red_s[4][64], red_d[4][64];

    const int tid = threadIdx.x;
    const int tx  = tid & 63;
    const int ty  = tid >> 6;

    const int raw = blockIdx.x;                 // 2048 = 8 XCD * 256 (bijective)
    const int wg  = (raw & 7) * 256 + (raw >> 3);
    const int chunk = wg & 3;
    const int bi    = wg >> 2;                  // b*256 + i
    const int i     = bi & (HGT - 1);
    const int b     = bi >> 8;
    const int j     = chunk * 64 + tx;
    const int hw    = i * WID + j;

    // stage x tile: wave ty loads ci planes [ty*16, ty*16+16)
    const float* xb = x + (size_t)b * CH * HW + hw;
    #pragma unroll
    for (int r = 0; r < 16; ++r) {
        const int ci = ty * 16 + r;
        xs[ci][tx] = xb[(size_t)ci * HW];
    }

    // rank-2 positional term, computed by threads 0..63 while others stage
    if (tid < CH) {
        float w0 = 0.f, w1 = 0.f, bc = 0.f;
        for (int ci = 0; ci < CH; ++ci) {
            float lwv = lin_w[ci * CH + tid];
            w0 = fmaf(pos_w[ci],      lwv, w0);
            w1 = fmaf(pos_w[CH + ci], lwv, w1);
            bc = fmaf(pos_b[ci],      lwv, bc);
        }
        W0[tid] = w0; W1[tid] = w1; Bc[tid] = bc;
    }
    __syncthreads();

    const int cob = __builtin_amdgcn_readfirstlane(ty) * 16;  // scalar co base

    float acc[16];
    #pragma unroll
    for (int k = 0; k < 16; ++k) acc[k] = 0.f;

    const float* lw = lin_w + cob;             // uniform -> s_load
    #pragma unroll
    for (int ci = 0; ci < CH; ++ci) {
        const float xv = xs[ci][tx];
        #pragma unroll
        for (int k = 0; k < 16; ++k)
            acc[k] = fmaf(xv, lw[ci * CH + k], acc[k]);
    }

    const float py  = -1.f + (2.f / 255.f) * (float)i;
    const float pxv = -1.f + (2.f / 255.f) * (float)j;

    float as = 0.f, ad = 0.f;
    unsigned pk[8];
    #pragma unroll
    for (int k = 0; k < 16; ++k) {
        const int co = cob + k;
        const float h = acc[k] + py * W0[co] + pxv * W1[co] + Bc[co];
        as = fmaf(h, att_src[co], as);
        ad = fmaf(h, att_dst[co], ad);
        const unsigned short bf = f2bf(h);
        if (k & 1) pk[k >> 1] |= (unsigned)bf << 16;
        else       pk[k >> 1]  = bf;
    }
    // store 4 quads (8B each), planar-by-quad -> coalesced 512B/wave
    uint2* hq = (uint2*)hfeat + (size_t)(b * 16 + (cob >> 2)) * HW + hw;
    #pragma unroll
    for (int qq = 0; qq < 4; ++qq)
        hq[(size_t)qq * HW] = make_uint2(pk[2 * qq], pk[2 * qq + 1]);

    red_s[ty][tx] = as; red_d[ty][tx] = ad;
    __syncthreads();
    if (ty == 0) {
        const int node = b * HW + hw;
        asrc[node] = red_s[0][tx] + red_s[1][tx] + red_s[2][tx] + red_s[3][tx];
        adst[node] = red_d[0][tx] + red_d[1][tx] + red_d[2][tx] + red_d[3][tx];
    }
}

// ---------------------------------------------------------------------------
// Kernel B: softmax over <=9 taps + weighted sum + bias.
// Thread = (pixel, channel-quad): 4 channels -> 9 uint2 loads, 36 FMA.
// Grid 8192 (32 blocks/CU demand -> full occupancy, latency-tolerant).
// XCD swizzle keeps all blocks of one row-band on one XCD (hfeat L2 reuse).
// ---------------------------------------------------------------------------
__global__ __launch_bounds__(256) void gat_aggr(
    const unsigned short* __restrict__ hfeat, const float* __restrict__ asrc,
    const float* __restrict__ adst, const float* __restrict__ bias,
    float* __restrict__ out)
{
    const int tid = threadIdx.x;
    const int tx  = tid & 63;
    const int ty  = tid >> 6;

    const int raw = blockIdx.x;                 // 8192 = 8 XCD * 1024 (bijective)
    const int wg  = (raw & 7) * 1024 + (raw >> 3);
    const int qg    = wg & 3;
    const int chunk = (wg >> 2) & 3;
    const int bi    = wg >> 4;                  // b*256 + i
    const int i     = bi & (HGT - 1);
    const int b     = bi >> 8;
    const int j     = chunk * 64 + tx;
    const int hw    = i * WID + j;
    const int node  = b * HW + hw;
    const int q     = __builtin_amdgcn_readfirstlane(qg * 4 + ty);  // quad 0..15

    const float adv = adst[node];

    float w[9];
    int   off[9];
    float m = -1e30f;
    #pragma unroll
    for (int t = 0; t < 9; ++t) {
        const int dr = t / 3 - 1, dc = t % 3 - 1;
        const int r = i + dr, c = j + dc;
        const bool ok = (r >= 0) && (r < HGT) && (c >= 0) && (c < WID);
        off[t] = ok ? (dr * WID + dc) : 0;      // clamped -> in-bounds
        float ev = -1e30f;
        if (ok) {
            ev = asrc[node + off[t]] + adv;
            ev = (ev >= 0.f) ? ev : NEG_SLOPE * ev;
        }
        w[t] = ev;
        m = fmaxf(m, ev);
    }

    float s = 0.f;
    #pragma unroll
    for (int t = 0; t < 9; ++t) {
        const float p = (w[t] > -1e29f) ? __expf(w[t] - m) : 0.f;
        w[t] = p; s += p;
    }
    const float inv = 1.f / s;

    const uint2* hq = (const uint2*)hfeat + (size_t)(b * 16 + q) * HW + hw;

    float a0 = 0.f, a1 = 0.f, a2 = 0.f, a3 = 0.f;
    #pragma unroll
    for (int t = 0; t < 9; ++t) {
        const uint2 v  = hq[off[t]];
        const float wt = w[t] * inv;
        a0 = fmaf(wt, __uint_as_float(v.x << 16),         a0);
        a1 = fmaf(wt, __uint_as_float(v.x & 0xffff0000u), a1);
        a2 = fmaf(wt, __uint_as_float(v.y << 16),         a2);
        a3 = fmaf(wt, __uint_as_float(v.y & 0xffff0000u), a3);
    }

    float* ob = out + (size_t)(b * CH + q * 4) * HW + hw;
    ob[0 * (size_t)HW] = a0 + bias[q * 4 + 0];
    ob[1 * (size_t)HW] = a1 + bias[q * 4 + 1];
    ob[2 * (size_t)HW] = a2 + bias[q * 4 + 2];
    ob[3 * (size_t)HW] = a3 + bias[q * 4 + 3];
}

// ---------------------------------------------------------------------------
extern "C" void kernel_launch(void* const* d_in, const int* in_sizes, int n_in,
                              void* d_out, int out_size, void* d_ws, size_t ws_size,
                              hipStream_t stream) {
    const float* x       = (const float*)d_in[0];
    const float* pos_w   = (const float*)d_in[1];
    const float* pos_b   = (const float*)d_in[2];
    const float* lin_w   = (const float*)d_in[3];
    const float* att_src = (const float*)d_in[4];
    const float* att_dst = (const float*)d_in[5];
    const float* bias    = (const float*)d_in[6];
    // edge_src / edge_dst (d_in[7], d_in[8]) are implied by the fixed grid topology.

    float* out = (float*)d_out;
    unsigned short* hfeat = (unsigned short*)d_ws;          // NODES*64 bf16 = 16.8 MB
    float* asrc = (float*)((char*)d_ws + (size_t)NODES * CH * 2);
    float* adst = asrc + NODES;

    gat_feat<<<dim3(2048), dim3(256), 0, stream>>>(
        x, pos_w, pos_b, lin_w, att_src, att_dst, hfeat, asrc, adst);
    gat_aggr<<<dim3(8192), dim3(256), 0, stream>>>(
        hfeat, asrc, adst, bias, out);
}

// Round 4
// 125.926 us; speedup vs baseline: 1.1929x; 1.1929x over previous
//
#include <hip/hip_runtime.h>

// Problem constants
#define HGT 256
#define WID 256
#define CH  64
#define NB  2
#define HW  (HGT * WID)
#define NODES (NB * HW)
#define NEG_SLOPE 0.2f

typedef float f32x16 __attribute__((ext_vector_type(16)));
typedef short short8 __attribute__((ext_vector_type(8)));

__device__ __forceinline__ unsigned short f2bf(float f) {
    union { float f; unsigned u; } v; v.f = f;
    unsigned r = v.u + 0x7FFF + ((v.u >> 16) & 1);   // RNE
    return (unsigned short)(r >> 16);
}

// ---------------------------------------------------------------------------
// Kernel A (MFMA): hfeat^T[co][node] = W^T[co][ci] @ x^T[ci][node]  in bf16,
// epilogue adds rank-2 pe term (py*W0 + px*W1 + Bc) in fp32, computes
// a_src/a_dst dots, stores hfeat as packed bf16 channel-quads.
// Block = 512 thr = 8 waves; each wave owns one 32-node group (all of co,K).
// W^T staged once per block in LDS (bf16, XOR-swizzled -> conflict-free
// ds_read_b128 A-fragments). X loads are direct global->VGPR (used once).
// MFMA: v_mfma_f32_32x32x16_bf16; D layout col=lane&31 (node),
// row=(reg&3)+8*(reg>>2)+4*(lane>>5) -> each reg-quad = one channel quad.
// ---------------------------------------------------------------------------
__global__ __launch_bounds__(512) void gat_feat(
    const float* __restrict__ x, const float* __restrict__ pos_w,
    const float* __restrict__ pos_b, const float* __restrict__ lin_w,
    const float* __restrict__ att_src, const float* __restrict__ att_dst,
    unsigned short* __restrict__ hfeat, float* __restrict__ asrc,
    float* __restrict__ adst)
{
    __shared__ __align__(16) unsigned char wlds[CH * 128];  // bf16 W^T [co][ci], swizzled
    __shared__ __align__(16) float W0s[CH], W1s[CH], Bcs[CH], atts[CH], attd[CH];

    const int tid  = threadIdx.x;
    const int lane = tid & 63;
    const int wid  = tid >> 6;        // wave 0..7
    const int hi   = lane >> 5;       // lane half
    const int col  = lane & 31;       // node within group / M-row within tile

    // ---- stage W^T to LDS as bf16, swizzled: byte = co*128 + (2*ci ^ ((co&7)<<4))
    {
        const int co  = tid & 63;
        const int cib = (tid >> 6) * 8;              // 8 ci per thread
        unsigned char* rowp = wlds + co * 128;
        const unsigned sw = (unsigned)((co & 7) << 4);
        #pragma unroll
        for (int p = 0; p < 4; ++p) {
            const int ci = cib + 2 * p;
            const unsigned lo = f2bf(lin_w[ci * CH + co]);          // coalesced over co
            const unsigned hh = f2bf(lin_w[(ci + 1) * CH + co]);
            *(unsigned*)(rowp + (((unsigned)(2 * ci)) ^ sw)) = lo | (hh << 16);
        }
    }
    // ---- rank-2 positional term (threads 0..63) + att vectors to LDS
    if (tid < CH) {
        float w0 = 0.f, w1 = 0.f, bc = 0.f;
        for (int ci = 0; ci < CH; ++ci) {
            const float lwv = lin_w[ci * CH + tid];
            w0 = fmaf(pos_w[ci],      lwv, w0);
            w1 = fmaf(pos_w[CH + ci], lwv, w1);
            bc = fmaf(pos_b[ci],      lwv, bc);
        }
        W0s[tid] = w0; W1s[tid] = w1; Bcs[tid] = bc;
    } else if (tid < 128) {
        atts[tid - 64] = att_src[tid - 64];
    } else if (tid < 192) {
        attd[tid - 128] = att_dst[tid - 128];
    }
    __syncthreads();

    // ---- hoist A-fragments (weights) from LDS: a[t][ks], t = co-tile (0-31 / 32-63)
    short8 a0[4], a1[4];
    {
        const unsigned sw = (unsigned)((col & 7) << 4);
        #pragma unroll
        for (int ks = 0; ks < 4; ++ks) {
            const unsigned off = (unsigned)(32 * ks + 16 * hi) ^ sw;
            a0[ks] = *(const short8*)(wlds + col * 128 + off);          // co = col
            a1[ks] = *(const short8*)(wlds + (32 + col) * 128 + off);   // co = 32+col
        }
    }

    // ---- this wave's 32-node group
    const int g     = blockIdx.x * 8 + wid;       // 0..4095
    const int node0 = g * 32;
    const int b     = node0 >> 16;                // node0 / HW
    const int hw    = (node0 & (HW - 1)) + col;
    const int node  = node0 + col;

    // ---- B-fragments: x^T[ci][node], ci = 16*ks + 8*hi + e  (32 indep loads)
    const float* xp = x + (size_t)b * CH * HW + hw;
    float xv[32];
    #pragma unroll
    for (int ks = 0; ks < 4; ++ks)
        #pragma unroll
        for (int e = 0; e < 8; ++e)
            xv[ks * 8 + e] = xp[(size_t)(16 * ks + 8 * hi + e) * HW];

    short8 bk[4];
    #pragma unroll
    for (int ks = 0; ks < 4; ++ks)
        #pragma unroll
        for (int e = 0; e < 8; ++e)
            bk[ks][e] = (short)f2bf(xv[ks * 8 + e]);

    f32x16 acc0, acc1;
    #pragma unroll
    for (int k = 0; k < 16; ++k) { acc0[k] = 0.f; acc1[k] = 0.f; }

    #pragma unroll
    for (int ks = 0; ks < 4; ++ks) {
        acc0 = __builtin_amdgcn_mfma_f32_32x32x16_bf16(a0[ks], bk[ks], acc0, 0, 0, 0);
        acc1 = __builtin_amdgcn_mfma_f32_32x32x16_bf16(a1[ks], bk[ks], acc1, 0, 0, 0);
    }

    // ---- epilogue: pe correction, att dots, pack bf16 quads
    const int ii = hw >> 8, jj = hw & 255;
    const float py = -1.f + (2.f / 255.f) * (float)ii;
    const float px = -1.f + (2.f / 255.f) * (float)jj;

    uint2* hq = (uint2*)hfeat + (size_t)b * 16 * HW + hw;
    float as = 0.f, ad = 0.f;

    #pragma unroll
    for (int t = 0; t < 2; ++t) {
        const f32x16 A = (t == 0) ? acc0 : acc1;
        #pragma unroll
        for (int q2 = 0; q2 < 4; ++q2) {
            const int cb = 32 * t + 8 * q2 + 4 * hi;   // channel-quad base
            const float4 w0 = *(const float4*)&W0s[cb];
            const float4 w1 = *(const float4*)&W1s[cb];
            const float4 bc = *(const float4*)&Bcs[cb];
            const float4 s4 = *(const float4*)&atts[cb];
            const float4 d4 = *(const float4*)&attd[cb];
            const float h0 = A[4 * q2 + 0] + py * w0.x + px * w1.x + bc.x;
            const float h1 = A[4 * q2 + 1] + py * w0.y + px * w1.y + bc.y;
            const float h2 = A[4 * q2 + 2] + py * w0.z + px * w1.z + bc.z;
            const float h3 = A[4 * q2 + 3] + py * w0.w + px * w1.w + bc.w;
            as += h0 * s4.x + h1 * s4.y + h2 * s4.z + h3 * s4.w;
            ad += h0 * d4.x + h1 * d4.y + h2 * d4.z + h3 * d4.w;
            const unsigned u0 = (unsigned)f2bf(h0) | ((unsigned)f2bf(h1) << 16);
            const unsigned u1 = (unsigned)f2bf(h2) | ((unsigned)f2bf(h3) << 16);
            const int q = 8 * t + 2 * q2 + hi;         // quad index = cb/4
            hq[(size_t)q * HW] = make_uint2(u0, u1);
        }
    }

    as += __shfl_xor(as, 32);
    ad += __shfl_xor(ad, 32);
    if (hi == 0) { asrc[node] = as; adst[node] = ad; }
}

// ---------------------------------------------------------------------------
// Kernel B (unchanged from round 3): softmax over <=9 taps + weighted sum.
// Thread = (pixel, channel-quad): 9 uint2 loads, 36 FMA. Grid 8192, XCD-swizzled.
// ---------------------------------------------------------------------------
__global__ __launch_bounds__(256) void gat_aggr(
    const unsigned short* __restrict__ hfeat, const float* __restrict__ asrc,
    const float* __restrict__ adst, const float* __restrict__ bias,
    float* __restrict__ out)
{
    const int tid = threadIdx.x;
    const int tx  = tid & 63;
    const int ty  = tid >> 6;

    const int raw = blockIdx.x;                 // 8192 = 8 XCD * 1024 (bijective)
    const int wg  = (raw & 7) * 1024 + (raw >> 3);
    const int qg    = wg & 3;
    const int chunk = (wg >> 2) & 3;
    const int bi    = wg >> 4;                  // b*256 + i
    const int i     = bi & (HGT - 1);
    const int b     = bi >> 8;
    const int j     = chunk * 64 + tx;
    const int hw    = i * WID + j;
    const int node  = b * HW + hw;
    const int q     = __builtin_amdgcn_readfirstlane(qg * 4 + ty);  // quad 0..15

    const float adv = adst[node];

    float w[9];
    int   off[9];
    float m = -1e30f;
    #pragma unroll
    for (int t = 0; t < 9; ++t) {
        const int dr = t / 3 - 1, dc = t % 3 - 1;
        const int r = i + dr, c = j + dc;
        const bool ok = (r >= 0) && (r < HGT) && (c >= 0) && (c < WID);
        off[t] = ok ? (dr * WID + dc) : 0;      // clamped -> in-bounds
        float ev = -1e30f;
        if (ok) {
            ev = asrc[node + off[t]] + adv;
            ev = (ev >= 0.f) ? ev : NEG_SLOPE * ev;
        }
        w[t] = ev;
        m = fmaxf(m, ev);
    }

    float s = 0.f;
    #pragma unroll
    for (int t = 0; t < 9; ++t) {
        const float p = (w[t] > -1e29f) ? __expf(w[t] - m) : 0.f;
        w[t] = p; s += p;
    }
    const float inv = 1.f / s;

    const uint2* hq = (const uint2*)hfeat + (size_t)(b * 16 + q) * HW + hw;

    float a0 = 0.f, a1 = 0.f, a2 = 0.f, a3 = 0.f;
    #pragma unroll
    for (int t = 0; t < 9; ++t) {
        const uint2 v  = hq[off[t]];
        const float wt = w[t] * inv;
        a0 = fmaf(wt, __uint_as_float(v.x << 16),         a0);
        a1 = fmaf(wt, __uint_as_float(v.x & 0xffff0000u), a1);
        a2 = fmaf(wt, __uint_as_float(v.y << 16),         a2);
        a3 = fmaf(wt, __uint_as_float(v.y & 0xffff0000u), a3);
    }

    float* ob = out + (size_t)(b * CH + q * 4) * HW + hw;
    ob[0 * (size_t)HW] = a0 + bias[q * 4 + 0];
    ob[1 * (size_t)HW] = a1 + bias[q * 4 + 1];
    ob[2 * (size_t)HW] = a2 + bias[q * 4 + 2];
    ob[3 * (size_t)HW] = a3 + bias[q * 4 + 3];
}

// ---------------------------------------------------------------------------
extern "C" void kernel_launch(void* const* d_in, const int* in_sizes, int n_in,
                              void* d_out, int out_size, void* d_ws, size_t ws_size,
                              hipStream_t stream) {
    const float* x       = (const float*)d_in[0];
    const float* pos_w   = (const float*)d_in[1];
    const float* pos_b   = (const float*)d_in[2];
    const float* lin_w   = (const float*)d_in[3];
    const float* att_src = (const float*)d_in[4];
    const float* att_dst = (const float*)d_in[5];
    const float* bias    = (const float*)d_in[6];
    // edge_src / edge_dst (d_in[7], d_in[8]) are implied by the fixed grid topology.

    float* out = (float*)d_out;
    unsigned short* hfeat = (unsigned short*)d_ws;          // NODES*64 bf16, quad-planar
    float* asrc = (float*)((char*)d_ws + (size_t)NODES * CH * 2);
    float* adst = asrc + NODES;

    gat_feat<<<dim3(512), dim3(512), 0, stream>>>(
        x, pos_w, pos_b, lin_w, att_src, att_dst, hfeat, asrc, adst);
    gat_aggr<<<dim3(8192), dim3(256), 0, stream>>>(
        hfeat, asrc, adst, bias, out);
}